// Round 1
// baseline (150.098 us; speedup 1.0000x reference)
//
#include <hip/hip_runtime.h>

// (B,N,D,L) = (32,1000,256,3), all fp32.
// d_in: [0]=x (unused), [1]=node_feature, [2]=Ws (L,D,D), [3]=bs (L,D).
// Math collapses (A_norm = ones/N):
//   h[b,:] = MLP(mean_n nf[b,n,:]);  out0 = nf + h (broadcast);  out1 = nf.
//
// R7: the timed window is dominated by harness poison fills (~41us, immovable)
// plus OUR 6 launches (~37us work + gaps). Restructured 6 -> 3 kernels:
//   K1: single HBM pass over nf -> out1 copy + partial colsums (no zero, no atomics)
//   K2: one 1024-thr block per b runs reduce + all 3 layers (was 3 launches)
//   K3: out0 = nf + h ; nf re-read is L3-resident (cheap FETCH)
#define BB 32
#define NN 1000
#define DD 256
#define SS 50              // node-axis splits; SS*RPS == NN
#define RPS 20             // rows per split
#define ELEMS (BB * NN * DD)   // 8,192,000 floats per output tensor

// ---- K1: partial column sums + out1 = nf, one coalesced float4 pass ----
// grid (SS, BB), 256 thr. Thread t: row-in-group r4 = t>>6, f4-col c = t&63.
__global__ __launch_bounds__(256) void k_colsum_copy(const float4* __restrict__ nf4,
                                                     float4* __restrict__ out1_4,
                                                     float* __restrict__ partials) {
    const int s = blockIdx.x, b = blockIdx.y, t = threadIdx.x;
    const int r4 = t >> 6, c = t & 63;
    float4 acc = make_float4(0.f, 0.f, 0.f, 0.f);
#pragma unroll
    for (int i = 0; i < RPS / 4; i++) {               // 5 iters of 4 rows
        const int n = s * RPS + i * 4 + r4;
        const int idx = (b * NN + n) * (DD / 4) + c;
        float4 v = nf4[idx];
        out1_4[idx] = v;                              // output 1 (= nf), same pass
        acc.x += v.x; acc.y += v.y; acc.z += v.z; acc.w += v.w;
    }
    __shared__ float red[1024];
    ((float4*)red)[r4 * 64 + c] = acc;                // red[r4*256 + c*4 + j]
    __syncthreads();
    // thread t owns dim d == t
    const float sum = red[t] + red[256 + t] + red[512 + t] + red[768 + t];
    partials[(b * SS + s) * DD + t] = sum;            // no atomics, no pre-zero
}

// ---- K2: whole MLP for one batch row per block. 1024 thr = 4 kq x 256 d. ----
// Each layer: thread (kq,d) accumulates 64 k-steps (W rows coalesced over d,
// L2-resident 256KB/layer), 4-way LDS reduce. Mean folded into layer-0 input.
__global__ __launch_bounds__(1024) void k_mlp(const float* __restrict__ partials,
                                              const float* __restrict__ Ws,
                                              const float* __restrict__ bsv,
                                              float* __restrict__ hrow) {
    const int b = blockIdx.x, t = threadIdx.x;
    const int d = t & (DD - 1), kq = t >> 8;
    __shared__ float h[DD];
    __shared__ float red[1024];

    // reduce the SS=50 partials -> mean
    float acc = 0.f;
    for (int s = kq; s < SS; s += 4)
        acc += partials[(b * SS + s) * DD + d];
    red[t] = acc;
    __syncthreads();
    if (kq == 0)
        h[d] = (red[d] + red[DD + d] + red[2 * DD + d] + red[3 * DD + d]) * (1.0f / (float)NN);
    __syncthreads();

    for (int l = 0; l < 3; l++) {
        const float* __restrict__ W = Ws + l * DD * DD;
        float a = 0.f;
#pragma unroll 16
        for (int kk = 0; kk < 64; kk++) {
            const int k = kq * 64 + kk;
            a += h[k] * W[k * DD + d];                // lanes span d: coalesced
        }
        __syncthreads();                              // all h reads of layer l done
        red[t] = a;
        __syncthreads();
        if (kq == 0) {
            float o = red[d] + red[DD + d] + red[2 * DD + d] + red[3 * DD + d]
                      + bsv[l * DD + d];
            if (l < 2) o = fmaxf(o, 0.f);
            if (l == 2) hrow[b * DD + d] = o;
            else        h[d] = o;
        }
        __syncthreads();
    }
}

// ---- K3: out0 = nf + broadcast(h). nf is L3-resident after K1. ----
__global__ __launch_bounds__(256) void k_out0(const float4* __restrict__ nf4,
                                              const float* __restrict__ hrow,
                                              float4* __restrict__ out0_4) {
    const int i = blockIdx.x * 256 + threadIdx.x;     // float4-chunk id, 2,048,000
    const int e = i * 4;
    const int b = e / (NN * DD);
    const int d0 = e & (DD - 1);                      // multiple of 4
    float4 v = nf4[i];
    float4 hv = *(const float4*)(hrow + b * DD + d0);
    out0_4[i] = make_float4(v.x + hv.x, v.y + hv.y, v.z + hv.z, v.w + hv.w);
}

extern "C" void kernel_launch(void* const* d_in, const int* in_sizes, int n_in,
                              void* d_out, int out_size, void* d_ws, size_t ws_size,
                              hipStream_t stream) {
    const float* nf  = (const float*)d_in[1];   // node_feature
    const float* Ws  = (const float*)d_in[2];   // (L,D,D)
    const float* bsv = (const float*)d_in[3];   // (L,D)
    float* out = (float*)d_out;

    float* partials = (float*)d_ws;             // BB*SS*DD floats (1.6 MB)
    float* hrow     = partials + BB * SS * DD;  // BB*DD floats

    k_colsum_copy<<<dim3(SS, BB), 256, 0, stream>>>((const float4*)nf,
                                                    (float4*)(out + ELEMS), partials);
    k_mlp<<<BB, 1024, 0, stream>>>(partials, Ws, bsv, hrow);
    k_out0<<<(ELEMS / 4) / 256, 256, 0, stream>>>((const float4*)nf, hrow, (float4*)out);
}